// Round 7
// baseline (290.231 us; speedup 1.0000x reference)
//
#include <hip/hip_runtime.h>
#include <hip/hip_bf16.h>
#include <math.h>

typedef __attribute__((ext_vector_type(8))) short short8;
typedef __attribute__((ext_vector_type(4))) float f32x4;

#define NB 32
#define ND 512
#define NC 512
#define NROW (NB*NC)   // 16384

__device__ __forceinline__ float bf2f(short u){
  union { float f; unsigned int i; } w; w.i = ((unsigned int)(unsigned short)u) << 16; return w.f;
}
__device__ __forceinline__ short f2bf(float f){
  union { float f; unsigned int i; } w; w.f = f;
  unsigned int x = w.i;
  return (short)((x + 0x7fffu + ((x >> 16) & 1u)) >> 16);  // RNE
}

// async global->LDS, 16B per lane; LDS dest = wave-uniform base + lane*16
__device__ __forceinline__ void gload16(const short* g, short* l){
  __builtin_amdgcn_global_load_lds(
      (const __attribute__((address_space(1))) unsigned int*)(uintptr_t)g,
      (__attribute__((address_space(3))) unsigned int*)(unsigned int)(uintptr_t)l,
      16, 0, 0);
}

// ---------------- fused pre-pass: input transpose + all weight prep ----------------
__global__ __launch_bounds__(256)
void pre_k(const float* __restrict__ res, short* __restrict__ Xb,
           const float* __restrict__ wk, const float* __restrict__ wq, const float* __restrict__ wv,
           const float* __restrict__ wo, const float* __restrict__ w1, const float* __restrict__ w2,
           const float* __restrict__ bq, const float* __restrict__ bv, const float* __restrict__ bo,
           short* __restrict__ wkT, short* __restrict__ wqT, short* __restrict__ wvT,
           short* __restrict__ woB, short* __restrict__ w1B, short* __restrict__ w2B,
           float* __restrict__ t2, float* __restrict__ c0v, float* __restrict__ s1col)
{
  __shared__ float t[64][65];
  const int blk = blockIdx.x;
  const int tid = threadIdx.x;
  if (blk < 2048){
    const int b = blk >> 6;
    const int d0 = ((blk >> 3) & 7) * 64;
    const int c0 = (blk & 7) * 64;
    const int j = tid & 63, i0 = tid >> 6;
    const float* src = res + (size_t)b * ND * NC;
#pragma unroll
    for (int p = 0; p < 16; p++){
      int i = p*4 + i0;
      t[i][j] = src[(size_t)(d0 + i) * NC + c0 + j];
    }
    __syncthreads();
#pragma unroll
    for (int p = 0; p < 16; p++){
      int i = p*4 + i0;
      Xb[((size_t)(b * NC + c0 + i)) * ND + d0 + j] = f2bf(t[j][i]);
    }
  } else if (blk < 2240){
    const int sb = blk - 2048;
    const int which = sb >> 6;
    const float* W = (which == 0) ? wk : (which == 1) ? wq : wv;
    short* Wt      = (which == 0) ? wkT : (which == 1) ? wqT : wvT;
    const int sub = sb & 63;
    const int r0 = (sub >> 3) * 64, c0 = (sub & 7) * 64;
    const int j = tid & 63, i0 = tid >> 6;
#pragma unroll
    for (int p = 0; p < 16; p++){
      int i = p*4 + i0;
      t[i][j] = W[(size_t)(r0 + i) * 512 + c0 + j];
    }
    __syncthreads();
#pragma unroll
    for (int p = 0; p < 16; p++){
      int i = p*4 + i0;
      Wt[(size_t)(c0 + i) * 512 + r0 + j] = f2bf(t[j][i]);
    }
  } else if (blk < 2880){
    const float* src; short* dst; int base;
    if (blk < 2368){ src = wo; dst = woB; base = blk - 2240; }
    else if (blk < 2624){ src = w1; dst = w1B; base = blk - 2368; }
    else { src = w2; dst = w2B; base = blk - 2624; }
    size_t i = ((size_t)base * 256 + tid) * 8;
    f32x4 a = *reinterpret_cast<const f32x4*>(&src[i]);
    f32x4 b = *reinterpret_cast<const f32x4*>(&src[i + 4]);
    short8 o;
#pragma unroll
    for (int k = 0; k < 4; k++) o[k] = f2bf(a[k]);
#pragma unroll
    for (int k = 0; k < 4; k++) o[4 + k] = f2bf(b[k]);
    *reinterpret_cast<short8*>(&dst[i]) = o;
  } else if (blk < 2882){
    int idx = (blk - 2880) * 256 + tid;
    float s = 0.f;
    for (int e = 0; e < 512; e++) s += bq[e] * wk[(size_t)e * 512 + idx];
    t2[idx] = s;
  } else if (blk < 2884){
    int idx = (blk - 2882) * 256 + tid;
    float s = bo[idx];
    for (int d = 0; d < 512; d++) s += wo[(size_t)idx * 512 + d] * bv[d];
    c0v[idx] = s;
  } else {
    int col = (blk - 2884) * 256 + tid;
    float s = 0.f;
    for (int d = 0; d < 512; d++) s += w1[(size_t)col * 512 + d];
    s1col[col] = s;
  }
}

// ---------------- GEMM: C[m][n] = sum_k A[m][k]*Bt[n][k], bf16 in, fp32 accum ----------------
// m97-exact structure: 128x128 tile, 4 waves (64x64 each, 4x4 acc), BK=64,
// SINGLE 32 KB LDS buffer, stage -> __syncthreads (vmcnt0 drain) -> compute ->
// __syncthreads, full K unroll. 5 blocks/CU: inter-block TLP hides the drain
// (m114). 1-D grid, bijective XCD swizzle when M/128 >= 8.
// EPI 0: +bias[col] -> bf16                                      (Y)
// EPI 1: +bias[col]+bf16 Xres -> bf16, BN-stat atomics           (H)
// EPI 2: gelu(alpha_r*acc + beta_r*s1col[col] + bias[col])->bf16 (G, BN folded)
// EPI 3: acc + bias[col] + alpha_r*Xres + beta_r -> bf16         (y, BN folded)
// EPI 4: plain -> bf16; grid.z selects second (A,Bt,Cb) set      (A_T, M)
template<int EPI, int M, int N, int K>
__global__ __launch_bounds__(256, 5)
void gemm_k(const short* __restrict__ A, const short* __restrict__ Bt,
            const short* __restrict__ A2, const short* __restrict__ Bt2,
            const float* __restrict__ bias,
            const short* __restrict__ Xres,
            short* __restrict__ Cb, short* __restrict__ Cb2,
            const float* __restrict__ bnw, const float* __restrict__ bnb,
            const float* __restrict__ s1col,
            float* __restrict__ bnsum, float* __restrict__ bnsumsq)
{
  if (EPI == 4 && blockIdx.z == 1){ A = A2; Bt = Bt2; Cb = Cb2; }
  __shared__ short As[8192];    // [128 rows][64 k], single buffer (32 KB total)
  __shared__ short Bs[8192];
  const int tid = threadIdx.x;
  const int lane = tid & 63;
  const int wave = tid >> 6;

  constexpr int NBN = N / 128;
  constexpr int MBM = M / 128;
  const int id = blockIdx.x;
  int bm, bn;
  if constexpr (MBM >= 8){
    // xcd = id&7 fixed while bn sweeps -> A panel reused NBN times on one XCD,
    // full B (<=1 MB) stays L2-resident per XCD.
    const int local = id >> 3;
    bn = (local % NBN) * 128;
    bm = ((local / NBN) * 8 + (id & 7)) * 128;
  } else {
    bn = (id % NBN) * 128;
    bm = (id / NBN) * 128;
  }

  const int wm = (wave >> 1) * 64;
  const int wn = (wave & 1) * 64;

  f32x4 acc[4][4];
#pragma unroll
  for (int i = 0; i < 4; i++)
#pragma unroll
    for (int j = 0; j < 4; j++) acc[i][j] = (f32x4){0.f, 0.f, 0.f, 0.f};

  // staging: wave w stages A rows [32w,32w+32) AND B rows [32w,32w+32): 4+4 gloads.
  // LDS written linearly; SOURCE K-granule pre-swizzled by row&7 so the
  // swizzled ds_read_b128 below is bank-conflict-free (both-sides rule #21).
  const int srow = lane >> 3;                    // row within 8-row group
  const int gcol = ((lane & 7) ^ srow) * 8;      // pre-swizzled granule (shorts)
  const short* ga = A  + (size_t)(bm + wave * 32 + srow) * K + gcol;
  const short* gb = Bt + (size_t)(bn + wave * 32 + srow) * K + gcol;
  short* la = As + wave * 2048;
  short* lb = Bs + wave * 2048;

  constexpr int nt = K >> 6;
#pragma unroll
  for (int t = 0; t < nt; ++t){
    const int kt = t << 6;
#pragma unroll
    for (int q = 0; q < 4; q++) gload16(ga + q * 8 * K + kt, la + q * 512);
#pragma unroll
    for (int q = 0; q < 4; q++) gload16(gb + q * 8 * K + kt, lb + q * 512);
    __syncthreads();                             // compiler drains vmcnt(0) here
#pragma unroll
    for (int kk = 0; kk < 2; kk++){
      short8 af[4], bfr[4];
      const int gl = kk * 4 + (lane >> 4);
      const int sw = (gl ^ (lane & 7)) * 8;      // row&7 == lane&7 for frag rows
#pragma unroll
      for (int i = 0; i < 4; i++)
        af[i]  = *reinterpret_cast<const short8*>(&As[(wm + i * 16 + (lane & 15)) * 64 + sw]);
#pragma unroll
      for (int j = 0; j < 4; j++)
        bfr[j] = *reinterpret_cast<const short8*>(&Bs[(wn + j * 16 + (lane & 15)) * 64 + sw]);
#pragma unroll
      for (int i = 0; i < 4; i++)
#pragma unroll
        for (int j = 0; j < 4; j++)
          acc[i][j] = __builtin_amdgcn_mfma_f32_16x16x32_bf16(af[i], bfr[j], acc[i][j], 0, 0, 0);
    }
    if (t + 1 < nt) __syncthreads();             // all reads done before restage
  }

  const int rb0 = bm + wm + ((lane >> 4) << 2);  // C/D: row=(lane>>4)*4+reg
  const int cb0 = bn + wn + (lane & 15);         // C/D: col=lane&15

  if (EPI == 1) {
    float* red = (float*)As;                     // reuse staging LDS
    __syncthreads();
#pragma unroll
    for (int i = 0; i < 4; i++){
#pragma unroll
      for (int r = 0; r < 4; r++){
        int row = rb0 + i * 16 + r;
        float s1 = 0.f, s2 = 0.f;
#pragma unroll
        for (int j = 0; j < 4; j++){
          int col = cb0 + j * 16;
          float v = acc[i][j][r] + bias[col] + bf2f(Xres[(size_t)row * N + col]);
          Cb[(size_t)row * N + col] = f2bf(v);
          s1 += v; s2 += v * v;
        }
#pragma unroll
        for (int mm = 1; mm < 16; mm <<= 1){ s1 += __shfl_xor(s1, mm, 64); s2 += __shfl_xor(s2, mm, 64); }
        if ((lane & 15) == 0){
          int g = lane >> 4;
          int idx = (((wave * 4 + i) * 4 + g) * 4 + r) * 2;
          red[idx] = s1; red[idx + 1] = s2;
        }
      }
    }
    __syncthreads();
    if (tid < 128){
      int rl = tid;
      int wg = rl >> 6, i = (rl >> 4) & 3, g = (rl >> 2) & 3, r = rl & 3;
      int i0 = ((((2 * wg + 0) * 4 + i) * 4 + g) * 4 + r) * 2;
      int i1 = ((((2 * wg + 1) * 4 + i) * 4 + g) * 4 + r) * 2;
      float s1 = red[i0] + red[i1];
      float s2 = red[i0 + 1] + red[i1 + 1];
      int c = (bm + rl) & (NC - 1);
      atomicAdd(&bnsum[c], s1);
      atomicAdd(&bnsumsq[c], s2);
    }
  } else {
#pragma unroll
    for (int i = 0; i < 4; i++){
      float al[4], be[4];
      if (EPI == 2 || EPI == 3){
#pragma unroll
        for (int r = 0; r < 4; r++){
          int c = (rb0 + i * 16 + r) & (NC - 1);
          float m = bnsum[c] * (1.0f / 16384.0f);
          float var = bnsumsq[c] * (1.0f / 16384.0f) - m * m;
          al[r] = rsqrtf(var + 1e-5f) * bnw[c];
          be[r] = bnb[c] - m * al[r];
        }
      }
#pragma unroll
      for (int j = 0; j < 4; j++){
        int col = cb0 + j * 16;
#pragma unroll
        for (int r = 0; r < 4; r++){
          int row = rb0 + i * 16 + r;
          float v = acc[i][j][r];
          if (EPI == 0) v += bias[col];
          else if (EPI == 2){
            v = al[r] * v + be[r] * s1col[col] + bias[col];
            v = 0.5f * v * (1.0f + erff(v * 0.70710678118654752f));
          }
          else if (EPI == 3){ v += bias[col] + al[r] * bf2f(Xres[(size_t)row * N + col]) + be[r]; }
          Cb[(size_t)row * N + col] = f2bf(v);
        }
      }
    }
  }
}

// ---------------- correlation + softmax(8) + z; Z overwrites Y in place ----------------
__global__ __launch_bounds__(256)
void attn_k(const short* __restrict__ Xb, short* __restrict__ YZ)
{
  __shared__ short xsh[4][512];
  const int lane = threadIdx.x & 63;
  const int wave = threadIdx.x >> 6;
  for (int it = 0; it < 4; ++it) {
    int row = (it * (int)gridDim.x + (int)blockIdx.x) * 4 + wave;
    short8 xv = *reinterpret_cast<const short8*>(&Xb[(size_t)row * 512 + lane * 8]);
    short8 yv = *reinterpret_cast<const short8*>(&YZ[(size_t)row * 512 + lane * 8]);
    *reinterpret_cast<short8*>(&xsh[wave][lane * 8]) = xv;   // per-wave slice
    float y[8];
#pragma unroll
    for (int i = 0; i < 8; i++) y[i] = bf2f(yv[i]);
    float xs[8][8];
    float sc[8];
#pragma unroll
    for (int s = 0; s < 8; s++){
      int off = (lane * 8 + 64 * s) & 511;
      short8 xr = *reinterpret_cast<const short8*>(&xsh[wave][off]);
      float p = 0.f;
#pragma unroll
      for (int i = 0; i < 8; i++){ float xf = bf2f(xr[i]); xs[s][i] = xf; p += y[i] * xf; }
#pragma unroll
      for (int mm = 1; mm < 64; mm <<= 1) p += __shfl_xor(p, mm, 64);
      sc[s] = p * 0.044194173824159216f;   // 512^-0.5
    }
    float mx = sc[0];
#pragma unroll
    for (int s = 1; s < 8; s++) mx = fmaxf(mx, sc[s]);
    float es[8], sum = 0.f;
#pragma unroll
    for (int s = 0; s < 8; s++){ es[s] = __expf(sc[s] - mx); sum += es[s]; }
    float inv = 1.0f / sum;
    float z[8] = {0.f,0.f,0.f,0.f,0.f,0.f,0.f,0.f};
#pragma unroll
    for (int s = 0; s < 8; s++){
      float a = es[s] * inv;
#pragma unroll
      for (int i = 0; i < 8; i++) z[i] += a * xs[s][i];
    }
    short8 zv;
#pragma unroll
    for (int i = 0; i < 8; i++) zv[i] = f2bf(z[i]);
    *reinterpret_cast<short8*>(&YZ[(size_t)row * 512 + lane * 8]) = zv;
  }
}

// ---------------- LayerNorm(512) + transposed output write ----------------
__global__ __launch_bounds__(256)
void ln_transpose_k(const short* __restrict__ Yb, const float* __restrict__ lnw,
                    const float* __restrict__ lnb, float* __restrict__ out)
{
  __shared__ short yn[64][520];
  const int tid = threadIdx.x;
  const int lane = tid & 63;
  const int wave = tid >> 6;
  const int b = blockIdx.x >> 3;
  const int c0 = (blockIdx.x & 7) * 64;
  float w8[8], bb8[8];
#pragma unroll
  for (int i = 0; i < 8; i++){ w8[i] = lnw[lane * 8 + i]; bb8[i] = lnb[lane * 8 + i]; }
  for (int rr = 0; rr < 16; rr++){
    int cl = wave * 16 + rr;
    int row = b * NC + c0 + cl;
    short8 yv = *reinterpret_cast<const short8*>(&Yb[(size_t)row * 512 + lane * 8]);
    float v[8]; float s = 0.f, s2 = 0.f;
#pragma unroll
    for (int i = 0; i < 8; i++){ v[i] = bf2f(yv[i]); s += v[i]; s2 += v[i] * v[i]; }
#pragma unroll
    for (int mm = 1; mm < 64; mm <<= 1){ s += __shfl_xor(s, mm, 64); s2 += __shfl_xor(s2, mm, 64); }
    float mean = s * (1.f / 512.f);
    float var = s2 * (1.f / 512.f) - mean * mean;
    float rs = rsqrtf(var + 1e-5f);
    short8 o;
#pragma unroll
    for (int i = 0; i < 8; i++) o[i] = f2bf((v[i] - mean) * rs * w8[i] + bb8[i]);
    *reinterpret_cast<short8*>(&yn[cl][lane * 8]) = o;
  }
  __syncthreads();
  size_t ob = (size_t)b * (ND * NC);
#pragma unroll 4
  for (int itx = 0; itx < 128; itx++){
    int idx = itx * 256 + tid;
    int d = idx >> 6;
    int cl = idx & 63;
    out[ob + (size_t)d * NC + c0 + cl] = bf2f(yn[cl][d]);
  }
}

extern "C" void kernel_launch(void* const* d_in, const int* in_sizes, int n_in,
                              void* d_out, int out_size, void* d_ws, size_t ws_size,
                              hipStream_t stream)
{
  const float* residual = (const float*)d_in[0];
  const float* wq   = (const float*)d_in[1];
  const float* bq   = (const float*)d_in[2];
  const float* wk   = (const float*)d_in[3];
  const float* wv   = (const float*)d_in[5];
  const float* bv   = (const float*)d_in[6];
  const float* wo   = (const float*)d_in[7];
  const float* bo   = (const float*)d_in[8];
  const float* bn_w = (const float*)d_in[9];
  const float* bn_b = (const float*)d_in[10];
  const float* w1   = (const float*)d_in[11];
  const float* b1   = (const float*)d_in[12];
  const float* w2   = (const float*)d_in[13];
  const float* b2   = (const float*)d_in[14];
  const float* ln_w = (const float*)d_in[15];
  const float* ln_b = (const float*)d_in[16];

  char* ws = (char*)d_ws;
  short* Xb  = (short*)(ws);                        // 16 MiB  X bf16 [16384][512]
  short* YZ  = (short*)(ws + ((size_t)16 << 20));   // 16 MiB  Y -> Z -> y
  short* Hb  = (short*)(ws + ((size_t)32 << 20));   // 16 MiB  h bf16
  char*  wsw = ws + ((size_t)48 << 20);
  short* wkT = (short*)(wsw);
  short* wqT = (short*)(wsw + ((size_t)512 << 10));
  short* wvT = (short*)(wsw + ((size_t)1024 << 10));
  short* woB = (short*)(wsw + ((size_t)1536 << 10));
  short* w1B = (short*)(wsw + ((size_t)2048 << 10));
  short* w2B = (short*)(wsw + ((size_t)3072 << 10));
  short* AT  = (short*)(wsw + ((size_t)5120 << 10));
  short* MB  = (short*)(wsw + ((size_t)5632 << 10));
  float* t2  = (float*)(wsw + ((size_t)6144 << 10));
  float* c0v = (float*)(wsw + ((size_t)6144 << 10) + 2048);
  float* bnsum   = (float*)(wsw + ((size_t)6144 << 10) + 4096);
  float* bnsumsq = (float*)(wsw + ((size_t)6144 << 10) + 6144);
  float* s1col   = (float*)(wsw + ((size_t)6144 << 10) + 8192);   // 4 KiB (1024 f32)

  short* Gb = (short*)d_out;   // G bf16 16384x1024 = 32 MiB, lives in d_out until LN overwrites

  hipMemsetAsync(bnsum, 0, 4096, stream);

  // input transpose + weight prep, one launch
  pre_k<<<2888, 256, 0, stream>>>(residual, Xb, wk, wq, wv, wo, w1, w2, bq, bv, bo,
                                  wkT, wqT, wvT, woB, w1B, w2B, t2, c0v, s1col);

  // z=0: A_T[t][d]=sum_e wk[e][t]*wq[e][d]; z=1: M[e][t]=sum_d wo[e][d]*wv[d][t]
  gemm_k<4,512,512,512><<<dim3(16, 1, 2), 256, 0, stream>>>(wkT, wqT, woB, wvT,
      nullptr, nullptr, AT, MB, nullptr, nullptr, nullptr, nullptr, nullptr);

  // Y = X @ A_T^T + t2
  gemm_k<0,NROW,512,512><<<512, 256, 0, stream>>>(Xb, AT, nullptr, nullptr,
      t2, nullptr, YZ, nullptr, nullptr, nullptr, nullptr, nullptr, nullptr);
  // scores/softmax/z (in place Y->Z)
  attn_k<<<1024, 256, 0, stream>>>(Xb, YZ);
  // H = Z @ M^T + c0 + X (bf16); BN stats in fp32 pre-round
  gemm_k<1,NROW,512,512><<<512, 256, 0, stream>>>(YZ, MB, nullptr, nullptr,
      c0v, Xb, Hb, nullptr, nullptr, nullptr, nullptr, bnsum, bnsumsq);
  // G = gelu(alpha*(Hb @ W1^T) + beta*s1col + b1)   (BN folded into epilogue)
  gemm_k<2,NROW,1024,512><<<1024, 256, 0, stream>>>(Hb, w1B, nullptr, nullptr,
      b1, nullptr, Gb, nullptr, bn_w, bn_b, s1col, bnsum, bnsumsq);
  // y = G @ W2^T + b2 + alpha*Hb + beta
  gemm_k<3,NROW,512,1024><<<512, 256, 0, stream>>>(Gb, w2B, nullptr, nullptr,
      b2, Hb, YZ, nullptr, bn_w, bn_b, nullptr, bnsum, bnsumsq);
  // LayerNorm + transposed output
  ln_transpose_k<<<256, 256, 0, stream>>>(YZ, ln_w, ln_b, (float*)d_out);
}

// Round 8
// 183.252 us; speedup vs baseline: 1.5838x; 1.5838x over previous
//
#include <hip/hip_runtime.h>
#include <hip/hip_bf16.h>
#include <math.h>

typedef __attribute__((ext_vector_type(8))) short short8;
typedef __attribute__((ext_vector_type(4))) float f32x4;

#define NB 32
#define ND 512
#define NC 512
#define NROW (NB*NC)   // 16384

__device__ __forceinline__ float bf2f(short u){
  union { float f; unsigned int i; } w; w.i = ((unsigned int)(unsigned short)u) << 16; return w.f;
}
__device__ __forceinline__ short f2bf(float f){
  union { float f; unsigned int i; } w; w.f = f;
  unsigned int x = w.i;
  return (short)((x + 0x7fffu + ((x >> 16) & 1u)) >> 16);  // RNE
}

// async global->LDS, 16B per lane; LDS dest = wave-uniform base + lane*16
__device__ __forceinline__ void gload16(const short* g, short* l){
  __builtin_amdgcn_global_load_lds(
      (const __attribute__((address_space(1))) unsigned int*)(uintptr_t)g,
      (__attribute__((address_space(3))) unsigned int*)(unsigned int)(uintptr_t)l,
      16, 0, 0);
}

// ---------------- fused pre-pass: input transpose + all weight prep ----------------
__global__ __launch_bounds__(256)
void pre_k(const float* __restrict__ res, short* __restrict__ Xb,
           const float* __restrict__ wk, const float* __restrict__ wq, const float* __restrict__ wv,
           const float* __restrict__ wo, const float* __restrict__ w1, const float* __restrict__ w2,
           const float* __restrict__ bq, const float* __restrict__ bv, const float* __restrict__ bo,
           short* __restrict__ wkT, short* __restrict__ wqT, short* __restrict__ wvT,
           short* __restrict__ woB, short* __restrict__ w1B, short* __restrict__ w2B,
           float* __restrict__ t2, float* __restrict__ c0v, float* __restrict__ s1col)
{
  __shared__ float t[64][65];
  const int blk = blockIdx.x;
  const int tid = threadIdx.x;
  if (blk < 2048){
    const int b = blk >> 6;
    const int d0 = ((blk >> 3) & 7) * 64;
    const int c0 = (blk & 7) * 64;
    const int j = tid & 63, i0 = tid >> 6;
    const float* src = res + (size_t)b * ND * NC;
#pragma unroll
    for (int p = 0; p < 16; p++){
      int i = p*4 + i0;
      t[i][j] = src[(size_t)(d0 + i) * NC + c0 + j];
    }
    __syncthreads();
#pragma unroll
    for (int p = 0; p < 16; p++){
      int i = p*4 + i0;
      Xb[((size_t)(b * NC + c0 + i)) * ND + d0 + j] = f2bf(t[j][i]);
    }
  } else if (blk < 2240){
    const int sb = blk - 2048;
    const int which = sb >> 6;
    const float* W = (which == 0) ? wk : (which == 1) ? wq : wv;
    short* Wt      = (which == 0) ? wkT : (which == 1) ? wqT : wvT;
    const int sub = sb & 63;
    const int r0 = (sub >> 3) * 64, c0 = (sub & 7) * 64;
    const int j = tid & 63, i0 = tid >> 6;
#pragma unroll
    for (int p = 0; p < 16; p++){
      int i = p*4 + i0;
      t[i][j] = W[(size_t)(r0 + i) * 512 + c0 + j];
    }
    __syncthreads();
#pragma unroll
    for (int p = 0; p < 16; p++){
      int i = p*4 + i0;
      Wt[(size_t)(c0 + i) * 512 + r0 + j] = f2bf(t[j][i]);
    }
  } else if (blk < 2880){
    const float* src; short* dst; int base;
    if (blk < 2368){ src = wo; dst = woB; base = blk - 2240; }
    else if (blk < 2624){ src = w1; dst = w1B; base = blk - 2368; }
    else { src = w2; dst = w2B; base = blk - 2624; }
    size_t i = ((size_t)base * 256 + tid) * 8;
    f32x4 a = *reinterpret_cast<const f32x4*>(&src[i]);
    f32x4 b = *reinterpret_cast<const f32x4*>(&src[i + 4]);
    short8 o;
#pragma unroll
    for (int k = 0; k < 4; k++) o[k] = f2bf(a[k]);
#pragma unroll
    for (int k = 0; k < 4; k++) o[4 + k] = f2bf(b[k]);
    *reinterpret_cast<short8*>(&dst[i]) = o;
  } else if (blk < 2882){
    int idx = (blk - 2880) * 256 + tid;
    float s = 0.f;
    for (int e = 0; e < 512; e++) s += bq[e] * wk[(size_t)e * 512 + idx];
    t2[idx] = s;
  } else if (blk < 2884){
    int idx = (blk - 2882) * 256 + tid;
    float s = bo[idx];
    for (int d = 0; d < 512; d++) s += wo[(size_t)idx * 512 + d] * bv[d];
    c0v[idx] = s;
  } else {
    int col = (blk - 2884) * 256 + tid;
    float s = 0.f;
    for (int d = 0; d < 512; d++) s += w1[(size_t)col * 512 + d];
    s1col[col] = s;
  }
}

// ---------------- GEMM: C[m][n] = sum_k A[m][k]*Bt[n][k], bf16 in, fp32 accum ----------------
// m97 structure: 128x128 tile, 4 waves (64x64 each, 4x4 acc), BK=64, SINGLE 32 KB
// LDS buffer, stage -> __syncthreads (vmcnt0 drain) -> compute -> __syncthreads,
// full K unroll. __launch_bounds__(256,4): 128-VGPR budget fits the ~116-reg live
// set (acc 64 + frags 32 + 16 addr) with NO SPILL -> 4 blocks/CU of TLP hides the
// barrier drain (m114). R7's (256,5) forced a ~102-reg budget and spilled acc in
// the unrolled loop (WRITE_SIZE 98.7 MB vs 16 MB). 1-D grid, bijective XCD swizzle.
// EPI 0: +bias[col] -> bf16                                      (Y)
// EPI 1: +bias[col]+bf16 Xres -> bf16, BN-stat atomics           (H)
// EPI 2: gelu(alpha_r*acc + beta_r*s1col[col] + bias[col])->bf16 (G, BN folded)
// EPI 3: acc + bias[col] + alpha_r*Xres + beta_r -> bf16         (y, BN folded)
// EPI 4: plain -> bf16; grid.z selects second (A,Bt,Cb) set      (A_T, M)
template<int EPI, int M, int N, int K>
__global__ __launch_bounds__(256, 4)
void gemm_k(const short* __restrict__ A, const short* __restrict__ Bt,
            const short* __restrict__ A2, const short* __restrict__ Bt2,
            const float* __restrict__ bias,
            const short* __restrict__ Xres,
            short* __restrict__ Cb, short* __restrict__ Cb2,
            const float* __restrict__ bnw, const float* __restrict__ bnb,
            const float* __restrict__ s1col,
            float* __restrict__ bnsum, float* __restrict__ bnsumsq)
{
  if (EPI == 4 && blockIdx.z == 1){ A = A2; Bt = Bt2; Cb = Cb2; }
  __shared__ short As[8192];    // [128 rows][64 k], single buffer (32 KB total)
  __shared__ short Bs[8192];
  const int tid = threadIdx.x;
  const int lane = tid & 63;
  const int wave = tid >> 6;

  constexpr int NBN = N / 128;
  constexpr int MBM = M / 128;
  const int id = blockIdx.x;
  int bm, bn;
  if constexpr (MBM >= 8){
    // xcd = id&7 fixed while bn sweeps -> A panel reused NBN times on one XCD,
    // full B (<=1 MB) stays L2-resident per XCD.
    const int local = id >> 3;
    bn = (local % NBN) * 128;
    bm = ((local / NBN) * 8 + (id & 7)) * 128;
  } else {
    bn = (id % NBN) * 128;
    bm = (id / NBN) * 128;
  }

  const int wm = (wave >> 1) * 64;
  const int wn = (wave & 1) * 64;

  f32x4 acc[4][4];
#pragma unroll
  for (int i = 0; i < 4; i++)
#pragma unroll
    for (int j = 0; j < 4; j++) acc[i][j] = (f32x4){0.f, 0.f, 0.f, 0.f};

  // staging: wave w stages A rows [32w,32w+32) AND B rows [32w,32w+32): 4+4 gloads.
  // LDS written linearly; SOURCE K-granule pre-swizzled by row&7 so the
  // swizzled ds_read_b128 below is bank-conflict-free (both-sides rule #21).
  const int srow = lane >> 3;                    // row within 8-row group
  const int gcol = ((lane & 7) ^ srow) * 8;      // pre-swizzled granule (shorts)
  const short* ga = A  + (size_t)(bm + wave * 32 + srow) * K + gcol;
  const short* gb = Bt + (size_t)(bn + wave * 32 + srow) * K + gcol;
  short* la = As + wave * 2048;
  short* lb = Bs + wave * 2048;

  constexpr int nt = K >> 6;
#pragma unroll
  for (int t = 0; t < nt; ++t){
    const int kt = t << 6;
#pragma unroll
    for (int q = 0; q < 4; q++) gload16(ga + q * 8 * K + kt, la + q * 512);
#pragma unroll
    for (int q = 0; q < 4; q++) gload16(gb + q * 8 * K + kt, lb + q * 512);
    __syncthreads();                             // compiler drains vmcnt(0) here
#pragma unroll
    for (int kk = 0; kk < 2; kk++){
      short8 af[4], bfr[4];
      const int gl = kk * 4 + (lane >> 4);
      const int sw = (gl ^ (lane & 7)) * 8;      // row&7 == lane&7 for frag rows
#pragma unroll
      for (int i = 0; i < 4; i++)
        af[i]  = *reinterpret_cast<const short8*>(&As[(wm + i * 16 + (lane & 15)) * 64 + sw]);
#pragma unroll
      for (int j = 0; j < 4; j++)
        bfr[j] = *reinterpret_cast<const short8*>(&Bs[(wn + j * 16 + (lane & 15)) * 64 + sw]);
#pragma unroll
      for (int i = 0; i < 4; i++)
#pragma unroll
        for (int j = 0; j < 4; j++)
          acc[i][j] = __builtin_amdgcn_mfma_f32_16x16x32_bf16(af[i], bfr[j], acc[i][j], 0, 0, 0);
    }
    if (t + 1 < nt) __syncthreads();             // all reads done before restage
  }

  const int rb0 = bm + wm + ((lane >> 4) << 2);  // C/D: row=(lane>>4)*4+reg
  const int cb0 = bn + wn + (lane & 15);         // C/D: col=lane&15

  if (EPI == 1) {
    float* red = (float*)As;                     // reuse staging LDS
    __syncthreads();
#pragma unroll
    for (int i = 0; i < 4; i++){
#pragma unroll
      for (int r = 0; r < 4; r++){
        int row = rb0 + i * 16 + r;
        float s1 = 0.f, s2 = 0.f;
#pragma unroll
        for (int j = 0; j < 4; j++){
          int col = cb0 + j * 16;
          float v = acc[i][j][r] + bias[col] + bf2f(Xres[(size_t)row * N + col]);
          Cb[(size_t)row * N + col] = f2bf(v);
          s1 += v; s2 += v * v;
        }
#pragma unroll
        for (int mm = 1; mm < 16; mm <<= 1){ s1 += __shfl_xor(s1, mm, 64); s2 += __shfl_xor(s2, mm, 64); }
        if ((lane & 15) == 0){
          int g = lane >> 4;
          int idx = (((wave * 4 + i) * 4 + g) * 4 + r) * 2;
          red[idx] = s1; red[idx + 1] = s2;
        }
      }
    }
    __syncthreads();
    if (tid < 128){
      int rl = tid;
      int wg = rl >> 6, i = (rl >> 4) & 3, g = (rl >> 2) & 3, r = rl & 3;
      int i0 = ((((2 * wg + 0) * 4 + i) * 4 + g) * 4 + r) * 2;
      int i1 = ((((2 * wg + 1) * 4 + i) * 4 + g) * 4 + r) * 2;
      float s1 = red[i0] + red[i1];
      float s2 = red[i0 + 1] + red[i1 + 1];
      int c = (bm + rl) & (NC - 1);
      atomicAdd(&bnsum[c], s1);
      atomicAdd(&bnsumsq[c], s2);
    }
  } else {
#pragma unroll
    for (int i = 0; i < 4; i++){
      float al[4], be[4];
      if (EPI == 2 || EPI == 3){
#pragma unroll
        for (int r = 0; r < 4; r++){
          int c = (rb0 + i * 16 + r) & (NC - 1);
          float m = bnsum[c] * (1.0f / 16384.0f);
          float var = bnsumsq[c] * (1.0f / 16384.0f) - m * m;
          al[r] = rsqrtf(var + 1e-5f) * bnw[c];
          be[r] = bnb[c] - m * al[r];
        }
      }
#pragma unroll
      for (int j = 0; j < 4; j++){
        int col = cb0 + j * 16;
#pragma unroll
        for (int r = 0; r < 4; r++){
          int row = rb0 + i * 16 + r;
          float v = acc[i][j][r];
          if (EPI == 0) v += bias[col];
          else if (EPI == 2){
            v = al[r] * v + be[r] * s1col[col] + bias[col];
            v = 0.5f * v * (1.0f + erff(v * 0.70710678118654752f));
          }
          else if (EPI == 3){ v += bias[col] + al[r] * bf2f(Xres[(size_t)row * N + col]) + be[r]; }
          Cb[(size_t)row * N + col] = f2bf(v);
        }
      }
    }
  }
}

// ---------------- correlation + softmax(8) + z; Z overwrites Y in place ----------------
__global__ __launch_bounds__(256)
void attn_k(const short* __restrict__ Xb, short* __restrict__ YZ)
{
  __shared__ short xsh[4][512];
  const int lane = threadIdx.x & 63;
  const int wave = threadIdx.x >> 6;
  for (int it = 0; it < 4; ++it) {
    int row = (it * (int)gridDim.x + (int)blockIdx.x) * 4 + wave;
    short8 xv = *reinterpret_cast<const short8*>(&Xb[(size_t)row * 512 + lane * 8]);
    short8 yv = *reinterpret_cast<const short8*>(&YZ[(size_t)row * 512 + lane * 8]);
    *reinterpret_cast<short8*>(&xsh[wave][lane * 8]) = xv;   // per-wave slice
    float y[8];
#pragma unroll
    for (int i = 0; i < 8; i++) y[i] = bf2f(yv[i]);
    float xs[8][8];
    float sc[8];
#pragma unroll
    for (int s = 0; s < 8; s++){
      int off = (lane * 8 + 64 * s) & 511;
      short8 xr = *reinterpret_cast<const short8*>(&xsh[wave][off]);
      float p = 0.f;
#pragma unroll
      for (int i = 0; i < 8; i++){ float xf = bf2f(xr[i]); xs[s][i] = xf; p += y[i] * xf; }
#pragma unroll
      for (int mm = 1; mm < 64; mm <<= 1) p += __shfl_xor(p, mm, 64);
      sc[s] = p * 0.044194173824159216f;   // 512^-0.5
    }
    float mx = sc[0];
#pragma unroll
    for (int s = 1; s < 8; s++) mx = fmaxf(mx, sc[s]);
    float es[8], sum = 0.f;
#pragma unroll
    for (int s = 0; s < 8; s++){ es[s] = __expf(sc[s] - mx); sum += es[s]; }
    float inv = 1.0f / sum;
    float z[8] = {0.f,0.f,0.f,0.f,0.f,0.f,0.f,0.f};
#pragma unroll
    for (int s = 0; s < 8; s++){
      float a = es[s] * inv;
#pragma unroll
      for (int i = 0; i < 8; i++) z[i] += a * xs[s][i];
    }
    short8 zv;
#pragma unroll
    for (int i = 0; i < 8; i++) zv[i] = f2bf(z[i]);
    *reinterpret_cast<short8*>(&YZ[(size_t)row * 512 + lane * 8]) = zv;
  }
}

// ---------------- LayerNorm(512) + transposed output write ----------------
__global__ __launch_bounds__(256)
void ln_transpose_k(const short* __restrict__ Yb, const float* __restrict__ lnw,
                    const float* __restrict__ lnb, float* __restrict__ out)
{
  __shared__ short yn[64][520];
  const int tid = threadIdx.x;
  const int lane = tid & 63;
  const int wave = tid >> 6;
  const int b = blockIdx.x >> 3;
  const int c0 = (blockIdx.x & 7) * 64;
  float w8[8], bb8[8];
#pragma unroll
  for (int i = 0; i < 8; i++){ w8[i] = lnw[lane * 8 + i]; bb8[i] = lnb[lane * 8 + i]; }
  for (int rr = 0; rr < 16; rr++){
    int cl = wave * 16 + rr;
    int row = b * NC + c0 + cl;
    short8 yv = *reinterpret_cast<const short8*>(&Yb[(size_t)row * 512 + lane * 8]);
    float v[8]; float s = 0.f, s2 = 0.f;
#pragma unroll
    for (int i = 0; i < 8; i++){ v[i] = bf2f(yv[i]); s += v[i]; s2 += v[i] * v[i]; }
#pragma unroll
    for (int mm = 1; mm < 64; mm <<= 1){ s += __shfl_xor(s, mm, 64); s2 += __shfl_xor(s2, mm, 64); }
    float mean = s * (1.f / 512.f);
    float var = s2 * (1.f / 512.f) - mean * mean;
    float rs = rsqrtf(var + 1e-5f);
    short8 o;
#pragma unroll
    for (int i = 0; i < 8; i++) o[i] = f2bf((v[i] - mean) * rs * w8[i] + bb8[i]);
    *reinterpret_cast<short8*>(&yn[cl][lane * 8]) = o;
  }
  __syncthreads();
  size_t ob = (size_t)b * (ND * NC);
#pragma unroll 4
  for (int itx = 0; itx < 128; itx++){
    int idx = itx * 256 + tid;
    int d = idx >> 6;
    int cl = idx & 63;
    out[ob + (size_t)d * NC + c0 + cl] = bf2f(yn[cl][d]);
  }
}

extern "C" void kernel_launch(void* const* d_in, const int* in_sizes, int n_in,
                              void* d_out, int out_size, void* d_ws, size_t ws_size,
                              hipStream_t stream)
{
  const float* residual = (const float*)d_in[0];
  const float* wq   = (const float*)d_in[1];
  const float* bq   = (const float*)d_in[2];
  const float* wk   = (const float*)d_in[3];
  const float* wv   = (const float*)d_in[5];
  const float* bv   = (const float*)d_in[6];
  const float* wo   = (const float*)d_in[7];
  const float* bo   = (const float*)d_in[8];
  const float* bn_w = (const float*)d_in[9];
  const float* bn_b = (const float*)d_in[10];
  const float* w1   = (const float*)d_in[11];
  const float* b1   = (const float*)d_in[12];
  const float* w2   = (const float*)d_in[13];
  const float* b2   = (const float*)d_in[14];
  const float* ln_w = (const float*)d_in[15];
  const float* ln_b = (const float*)d_in[16];

  char* ws = (char*)d_ws;
  short* Xb  = (short*)(ws);                        // 16 MiB  X bf16 [16384][512]
  short* YZ  = (short*)(ws + ((size_t)16 << 20));   // 16 MiB  Y -> Z -> y
  short* Hb  = (short*)(ws + ((size_t)32 << 20));   // 16 MiB  h bf16
  char*  wsw = ws + ((size_t)48 << 20);
  short* wkT = (short*)(wsw);
  short* wqT = (short*)(wsw + ((size_t)512 << 10));
  short* wvT = (short*)(wsw + ((size_t)1024 << 10));
  short* woB = (short*)(wsw + ((size_t)1536 << 10));
  short* w1B = (short*)(wsw + ((size_t)2048 << 10));
  short* w2B = (short*)(wsw + ((size_t)3072 << 10));
  short* AT  = (short*)(wsw + ((size_t)5120 << 10));
  short* MB  = (short*)(wsw + ((size_t)5632 << 10));
  float* t2  = (float*)(wsw + ((size_t)6144 << 10));
  float* c0v = (float*)(wsw + ((size_t)6144 << 10) + 2048);
  float* bnsum   = (float*)(wsw + ((size_t)6144 << 10) + 4096);
  float* bnsumsq = (float*)(wsw + ((size_t)6144 << 10) + 6144);
  float* s1col   = (float*)(wsw + ((size_t)6144 << 10) + 8192);   // 4 KiB (1024 f32)

  short* Gb = (short*)d_out;   // G bf16 16384x1024 = 32 MiB, lives in d_out until LN overwrites

  hipMemsetAsync(bnsum, 0, 4096, stream);

  // input transpose + weight prep, one launch
  pre_k<<<2888, 256, 0, stream>>>(residual, Xb, wk, wq, wv, wo, w1, w2, bq, bv, bo,
                                  wkT, wqT, wvT, woB, w1B, w2B, t2, c0v, s1col);

  // z=0: A_T[t][d]=sum_e wk[e][t]*wq[e][d]; z=1: M[e][t]=sum_d wo[e][d]*wv[d][t]
  gemm_k<4,512,512,512><<<dim3(16, 1, 2), 256, 0, stream>>>(wkT, wqT, woB, wvT,
      nullptr, nullptr, AT, MB, nullptr, nullptr, nullptr, nullptr, nullptr);

  // Y = X @ A_T^T + t2
  gemm_k<0,NROW,512,512><<<512, 256, 0, stream>>>(Xb, AT, nullptr, nullptr,
      t2, nullptr, YZ, nullptr, nullptr, nullptr, nullptr, nullptr, nullptr);
  // scores/softmax/z (in place Y->Z)
  attn_k<<<1024, 256, 0, stream>>>(Xb, YZ);
  // H = Z @ M^T + c0 + X (bf16); BN stats in fp32 pre-round
  gemm_k<1,NROW,512,512><<<512, 256, 0, stream>>>(YZ, MB, nullptr, nullptr,
      c0v, Xb, Hb, nullptr, nullptr, nullptr, nullptr, bnsum, bnsumsq);
  // G = gelu(alpha*(Hb @ W1^T) + beta*s1col + b1)   (BN folded into epilogue)
  gemm_k<2,NROW,1024,512><<<1024, 256, 0, stream>>>(Hb, w1B, nullptr, nullptr,
      b1, nullptr, Gb, nullptr, bn_w, bn_b, s1col, bnsum, bnsumsq);
  // y = G @ W2^T + b2 + alpha*Hb + beta
  gemm_k<3,NROW,512,1024><<<512, 256, 0, stream>>>(Gb, w2B, nullptr, nullptr,
      b2, Hb, YZ, nullptr, bn_w, bn_b, nullptr, bnsum, bnsumsq);
  // LayerNorm + transposed output
  ln_transpose_k<<<256, 256, 0, stream>>>(YZ, ln_w, ln_b, (float*)d_out);
}

// Round 9
// 156.806 us; speedup vs baseline: 1.8509x; 1.1687x over previous
//
#include <hip/hip_runtime.h>
#include <hip/hip_bf16.h>
#include <math.h>

typedef __attribute__((ext_vector_type(8))) short short8;
typedef __attribute__((ext_vector_type(4))) float f32x4;

#define NB 32
#define ND 512
#define NC 512
#define NROW (NB*NC)   // 16384

__device__ __forceinline__ float bf2f(short u){
  union { float f; unsigned int i; } w; w.i = ((unsigned int)(unsigned short)u) << 16; return w.f;
}
__device__ __forceinline__ short f2bf(float f){
  union { float f; unsigned int i; } w; w.f = f;
  unsigned int x = w.i;
  return (short)((x + 0x7fffu + ((x >> 16) & 1u)) >> 16);  // RNE
}

// async global->LDS, 16B per lane; LDS dest = wave-uniform base + lane*16
__device__ __forceinline__ void gload16(const short* g, short* l){
  __builtin_amdgcn_global_load_lds(
      (const __attribute__((address_space(1))) unsigned int*)(uintptr_t)g,
      (__attribute__((address_space(3))) unsigned int*)(unsigned int)(uintptr_t)l,
      16, 0, 0);
}

// ---------------- fused pre-pass: input transpose + all weight prep ----------------
__global__ __launch_bounds__(256)
void pre_k(const float* __restrict__ res, short* __restrict__ Xb,
           const float* __restrict__ wk, const float* __restrict__ wq, const float* __restrict__ wv,
           const float* __restrict__ wo, const float* __restrict__ w1, const float* __restrict__ w2,
           const float* __restrict__ bq, const float* __restrict__ bv, const float* __restrict__ bo,
           short* __restrict__ wkT, short* __restrict__ wqT, short* __restrict__ wvT,
           short* __restrict__ woB, short* __restrict__ w1B, short* __restrict__ w2B,
           float* __restrict__ t2, float* __restrict__ c0v, float* __restrict__ s1col)
{
  __shared__ float t[64][65];
  const int blk = blockIdx.x;
  const int tid = threadIdx.x;
  if (blk < 2048){
    const int b = blk >> 6;
    const int d0 = ((blk >> 3) & 7) * 64;
    const int c0 = (blk & 7) * 64;
    const int j = tid & 63, i0 = tid >> 6;
    const float* src = res + (size_t)b * ND * NC;
#pragma unroll
    for (int p = 0; p < 16; p++){
      int i = p*4 + i0;
      t[i][j] = src[(size_t)(d0 + i) * NC + c0 + j];
    }
    __syncthreads();
#pragma unroll
    for (int p = 0; p < 16; p++){
      int i = p*4 + i0;
      Xb[((size_t)(b * NC + c0 + i)) * ND + d0 + j] = f2bf(t[j][i]);
    }
  } else if (blk < 2240){
    const int sb = blk - 2048;
    const int which = sb >> 6;
    const float* W = (which == 0) ? wk : (which == 1) ? wq : wv;
    short* Wt      = (which == 0) ? wkT : (which == 1) ? wqT : wvT;
    const int sub = sb & 63;
    const int r0 = (sub >> 3) * 64, c0 = (sub & 7) * 64;
    const int j = tid & 63, i0 = tid >> 6;
#pragma unroll
    for (int p = 0; p < 16; p++){
      int i = p*4 + i0;
      t[i][j] = W[(size_t)(r0 + i) * 512 + c0 + j];
    }
    __syncthreads();
#pragma unroll
    for (int p = 0; p < 16; p++){
      int i = p*4 + i0;
      Wt[(size_t)(c0 + i) * 512 + r0 + j] = f2bf(t[j][i]);
    }
  } else if (blk < 2880){
    const float* src; short* dst; int base;
    if (blk < 2368){ src = wo; dst = woB; base = blk - 2240; }
    else if (blk < 2624){ src = w1; dst = w1B; base = blk - 2368; }
    else { src = w2; dst = w2B; base = blk - 2624; }
    size_t i = ((size_t)base * 256 + tid) * 8;
    f32x4 a = *reinterpret_cast<const f32x4*>(&src[i]);
    f32x4 b = *reinterpret_cast<const f32x4*>(&src[i + 4]);
    short8 o;
#pragma unroll
    for (int k = 0; k < 4; k++) o[k] = f2bf(a[k]);
#pragma unroll
    for (int k = 0; k < 4; k++) o[4 + k] = f2bf(b[k]);
    *reinterpret_cast<short8*>(&dst[i]) = o;
  } else if (blk < 2882){
    int idx = (blk - 2880) * 256 + tid;
    float s = 0.f;
    for (int e = 0; e < 512; e++) s += bq[e] * wk[(size_t)e * 512 + idx];
    t2[idx] = s;
  } else if (blk < 2884){
    int idx = (blk - 2882) * 256 + tid;
    float s = bo[idx];
    for (int d = 0; d < 512; d++) s += wo[(size_t)idx * 512 + d] * bv[d];
    c0v[idx] = s;
  } else {
    int col = (blk - 2884) * 256 + tid;
    float s = 0.f;
    for (int d = 0; d < 512; d++) s += w1[(size_t)col * 512 + d];
    s1col[col] = s;
  }
}

// ---------------- GEMM: C[m][n] = sum_k A[m][k]*Bt[n][k], bf16 in, fp32 accum ----------------
// R6 structure (best measured): 128x128 tile, 4 waves (64x64 each, 4x4 acc), BK=64
// double-buffered (64 KB LDS), counted vmcnt(8) depth-2 pipeline (T4: loads stay in
// flight ACROSS barriers; never drain to 0 mid-loop), raw s_barrier, full K unroll,
// T5 setprio around the MFMA cluster. 1-D grid, bijective XCD swizzle.
// EPI 0: +bias[col] -> bf16                                      (Y)
// EPI 1: +bias[col]+bf16 Xres -> bf16, BN-stat atomics           (H)
// EPI 2: gelu_tanh(alpha_r*acc + beta_r*s1col[col] + bias[col])  (G, BN folded)
// EPI 3: acc + bias[col] + alpha_r*Xres + beta_r -> bf16         (y, BN folded)
// EPI 4: plain -> bf16; grid.z selects second (A,Bt,Cb) set      (A_T, M)
template<int EPI, int M, int N, int K>
__global__ __launch_bounds__(256, 2)
void gemm_k(const short* __restrict__ A, const short* __restrict__ Bt,
            const short* __restrict__ A2, const short* __restrict__ Bt2,
            const float* __restrict__ bias,
            const short* __restrict__ Xres,
            short* __restrict__ Cb, short* __restrict__ Cb2,
            const float* __restrict__ bnw, const float* __restrict__ bnb,
            const float* __restrict__ s1col,
            float* __restrict__ bnsum, float* __restrict__ bnsumsq)
{
  if (EPI == 4 && blockIdx.z == 1){ A = A2; Bt = Bt2; Cb = Cb2; }
  __shared__ short As[2][8192];    // [buf][128 rows][64 k]
  __shared__ short Bs[2][8192];
  const int tid = threadIdx.x;
  const int lane = tid & 63;
  const int wave = tid >> 6;

  constexpr int NBN = N / 128;
  constexpr int MBM = M / 128;
  const int id = blockIdx.x;
  int bm, bn;
  if constexpr (MBM >= 8){
    // xcd = id&7 fixed while bn sweeps -> A panel reused NBN times on one XCD,
    // full B (<=1 MB) stays L2-resident per XCD.
    const int local = id >> 3;
    bn = (local % NBN) * 128;
    bm = ((local / NBN) * 8 + (id & 7)) * 128;
  } else {
    bn = (id % NBN) * 128;
    bm = (id / NBN) * 128;
  }

  const int wm = (wave >> 1) * 64;
  const int wn = (wave & 1) * 64;

  f32x4 acc[4][4];
#pragma unroll
  for (int i = 0; i < 4; i++)
#pragma unroll
    for (int j = 0; j < 4; j++) acc[i][j] = (f32x4){0.f, 0.f, 0.f, 0.f};

  // staging: wave w stages A rows [32w,32w+32) AND B rows [32w,32w+32): 4+4 gloads.
  // LDS written linearly; SOURCE K-granule pre-swizzled by row&7 so the
  // swizzled ds_read_b128 below is bank-conflict-free (both-sides rule #21).
  const int srow = lane >> 3;                    // row within 8-row group
  const int gcol = ((lane & 7) ^ srow) * 8;      // pre-swizzled granule (shorts)
  const short* ga = A  + (size_t)(bm + wave * 32 + srow) * K + gcol;
  const short* gb = Bt + (size_t)(bn + wave * 32 + srow) * K + gcol;
  short* la0 = As[0] + wave * 2048; short* la1 = As[1] + wave * 2048;
  short* lb0 = Bs[0] + wave * 2048; short* lb1 = Bs[1] + wave * 2048;

  auto stage = [&](int buf, int kt){
    short* la = buf ? la1 : la0;
    short* lb = buf ? lb1 : lb0;
#pragma unroll
    for (int q = 0; q < 4; q++) gload16(ga + q * 8 * K + kt, la + q * 512);
#pragma unroll
    for (int q = 0; q < 4; q++) gload16(gb + q * 8 * K + kt, lb + q * 512);
  };

  stage(0, 0);
  stage(1, 64);

  constexpr int nt = K >> 6;
#pragma unroll
  for (int t = 0; t < nt; ++t){
    const int cur = t & 1;                       // compile-time under unroll
    if (t < nt - 1) asm volatile("s_waitcnt vmcnt(8)" ::: "memory");
    else            asm volatile("s_waitcnt vmcnt(0)" ::: "memory");
    __builtin_amdgcn_s_barrier();                // all waves' step-t loads landed
    __builtin_amdgcn_sched_barrier(0);
    __builtin_amdgcn_s_setprio(1);
    const short* as = As[cur];
    const short* bs = Bs[cur];
#pragma unroll
    for (int kk = 0; kk < 2; kk++){
      short8 af[4], bfr[4];
      const int gl = kk * 4 + (lane >> 4);
      const int sw = (gl ^ (lane & 7)) * 8;      // row&7 == lane&7 for frag rows
#pragma unroll
      for (int i = 0; i < 4; i++)
        af[i]  = *reinterpret_cast<const short8*>(&as[(wm + i * 16 + (lane & 15)) * 64 + sw]);
#pragma unroll
      for (int j = 0; j < 4; j++)
        bfr[j] = *reinterpret_cast<const short8*>(&bs[(wn + j * 16 + (lane & 15)) * 64 + sw]);
#pragma unroll
      for (int i = 0; i < 4; i++)
#pragma unroll
        for (int j = 0; j < 4; j++)
          acc[i][j] = __builtin_amdgcn_mfma_f32_16x16x32_bf16(af[i], bfr[j], acc[i][j], 0, 0, 0);
    }
    __builtin_amdgcn_s_setprio(0);
    __builtin_amdgcn_sched_barrier(0);
    __builtin_amdgcn_s_barrier();                // all waves done reading buf[cur]
    if (t + 2 < nt) stage(cur, (t + 2) << 6);    // refill just-freed buffer
  }

  const int rb0 = bm + wm + ((lane >> 4) << 2);  // C/D: row=(lane>>4)*4+reg
  const int cb0 = bn + wn + (lane & 15);         // C/D: col=lane&15

  if (EPI == 1) {
    float* red = (float*)As;                     // reuse staging LDS
#pragma unroll
    for (int i = 0; i < 4; i++){
#pragma unroll
      for (int r = 0; r < 4; r++){
        int row = rb0 + i * 16 + r;
        float s1 = 0.f, s2 = 0.f;
#pragma unroll
        for (int j = 0; j < 4; j++){
          int col = cb0 + j * 16;
          float v = acc[i][j][r] + bias[col] + bf2f(Xres[(size_t)row * N + col]);
          Cb[(size_t)row * N + col] = f2bf(v);
          s1 += v; s2 += v * v;
        }
#pragma unroll
        for (int mm = 1; mm < 16; mm <<= 1){ s1 += __shfl_xor(s1, mm, 64); s2 += __shfl_xor(s2, mm, 64); }
        if ((lane & 15) == 0){
          int g = lane >> 4;
          int idx = (((wave * 4 + i) * 4 + g) * 4 + r) * 2;
          red[idx] = s1; red[idx + 1] = s2;
        }
      }
    }
    __syncthreads();
    if (tid < 128){
      int rl = tid;
      int wg = rl >> 6, i = (rl >> 4) & 3, g = (rl >> 2) & 3, r = rl & 3;
      int i0 = ((((2 * wg + 0) * 4 + i) * 4 + g) * 4 + r) * 2;
      int i1 = ((((2 * wg + 1) * 4 + i) * 4 + g) * 4 + r) * 2;
      float s1 = red[i0] + red[i1];
      float s2 = red[i0 + 1] + red[i1 + 1];
      int c = (bm + rl) & (NC - 1);
      atomicAdd(&bnsum[c], s1);
      atomicAdd(&bnsumsq[c], s2);
    }
  } else {
#pragma unroll
    for (int i = 0; i < 4; i++){
      float al[4], be[4];
      if (EPI == 2 || EPI == 3){
#pragma unroll
        for (int r = 0; r < 4; r++){
          int c = (rb0 + i * 16 + r) & (NC - 1);
          float m = bnsum[c] * (1.0f / 16384.0f);
          float var = bnsumsq[c] * (1.0f / 16384.0f) - m * m;
          al[r] = rsqrtf(var + 1e-5f) * bnw[c];
          be[r] = bnb[c] - m * al[r];
        }
      }
#pragma unroll
      for (int j = 0; j < 4; j++){
        int col = cb0 + j * 16;
#pragma unroll
        for (int r = 0; r < 4; r++){
          int row = rb0 + i * 16 + r;
          float v = acc[i][j][r];
          if (EPI == 0) v += bias[col];
          else if (EPI == 2){
            v = al[r] * v + be[r] * s1col[col] + bias[col];
            // tanh-approx GELU (max dev ~1e-3 vs erf form; VALU-cheap)
            float u = 0.79788456080286535f * (v + 0.044715f * v * v * v);
            float e = __expf(-2.0f * fabsf(u));
            float th = __builtin_copysignf((1.0f - e) / (1.0f + e), u);
            v = 0.5f * v * (1.0f + th);
          }
          else if (EPI == 3){ v += bias[col] + al[r] * bf2f(Xres[(size_t)row * N + col]) + be[r]; }
          Cb[(size_t)row * N + col] = f2bf(v);
        }
      }
    }
  }
}

// ---------------- correlation + softmax(8) + z; Z overwrites Y in place ----------------
__global__ __launch_bounds__(256)
void attn_k(const short* __restrict__ Xb, short* __restrict__ YZ)
{
  __shared__ short xsh[4][512];
  const int lane = threadIdx.x & 63;
  const int wave = threadIdx.x >> 6;
  for (int it = 0; it < 4; ++it) {
    int row = (it * (int)gridDim.x + (int)blockIdx.x) * 4 + wave;
    short8 xv = *reinterpret_cast<const short8*>(&Xb[(size_t)row * 512 + lane * 8]);
    short8 yv = *reinterpret_cast<const short8*>(&YZ[(size_t)row * 512 + lane * 8]);
    *reinterpret_cast<short8*>(&xsh[wave][lane * 8]) = xv;   // per-wave slice
    float y[8];
#pragma unroll
    for (int i = 0; i < 8; i++) y[i] = bf2f(yv[i]);
    float xs[8][8];
    float sc[8];
#pragma unroll
    for (int s = 0; s < 8; s++){
      int off = (lane * 8 + 64 * s) & 511;
      short8 xr = *reinterpret_cast<const short8*>(&xsh[wave][off]);
      float p = 0.f;
#pragma unroll
      for (int i = 0; i < 8; i++){ float xf = bf2f(xr[i]); xs[s][i] = xf; p += y[i] * xf; }
#pragma unroll
      for (int mm = 1; mm < 64; mm <<= 1) p += __shfl_xor(p, mm, 64);
      sc[s] = p * 0.044194173824159216f;   // 512^-0.5
    }
    float mx = sc[0];
#pragma unroll
    for (int s = 1; s < 8; s++) mx = fmaxf(mx, sc[s]);
    float es[8], sum = 0.f;
#pragma unroll
    for (int s = 0; s < 8; s++){ es[s] = __expf(sc[s] - mx); sum += es[s]; }
    float inv = 1.0f / sum;
    float z[8] = {0.f,0.f,0.f,0.f,0.f,0.f,0.f,0.f};
#pragma unroll
    for (int s = 0; s < 8; s++){
      float a = es[s] * inv;
#pragma unroll
      for (int i = 0; i < 8; i++) z[i] += a * xs[s][i];
    }
    short8 zv;
#pragma unroll
    for (int i = 0; i < 8; i++) zv[i] = f2bf(z[i]);
    *reinterpret_cast<short8*>(&YZ[(size_t)row * 512 + lane * 8]) = zv;
  }
}

// ---------------- LayerNorm(512) + transposed output write (8 waves/block) ----------------
__global__ __launch_bounds__(512)
void ln_transpose_k(const short* __restrict__ Yb, const float* __restrict__ lnw,
                    const float* __restrict__ lnb, float* __restrict__ out)
{
  __shared__ short yn[64][520];
  const int tid = threadIdx.x;
  const int lane = tid & 63;
  const int wave = tid >> 6;     // 0..7
  const int b = blockIdx.x >> 3;
  const int c0 = (blockIdx.x & 7) * 64;
  float w8[8], bb8[8];
#pragma unroll
  for (int i = 0; i < 8; i++){ w8[i] = lnw[lane * 8 + i]; bb8[i] = lnb[lane * 8 + i]; }
  for (int rr = 0; rr < 8; rr++){
    int cl = wave * 8 + rr;
    int row = b * NC + c0 + cl;
    short8 yv = *reinterpret_cast<const short8*>(&Yb[(size_t)row * 512 + lane * 8]);
    float v[8]; float s = 0.f, s2 = 0.f;
#pragma unroll
    for (int i = 0; i < 8; i++){ v[i] = bf2f(yv[i]); s += v[i]; s2 += v[i] * v[i]; }
#pragma unroll
    for (int mm = 1; mm < 64; mm <<= 1){ s += __shfl_xor(s, mm, 64); s2 += __shfl_xor(s2, mm, 64); }
    float mean = s * (1.f / 512.f);
    float var = s2 * (1.f / 512.f) - mean * mean;
    float rs = rsqrtf(var + 1e-5f);
    short8 o;
#pragma unroll
    for (int i = 0; i < 8; i++) o[i] = f2bf((v[i] - mean) * rs * w8[i] + bb8[i]);
    *reinterpret_cast<short8*>(&yn[cl][lane * 8]) = o;
  }
  __syncthreads();
  size_t ob = (size_t)b * (ND * NC);
#pragma unroll 4
  for (int itx = 0; itx < 64; itx++){
    int idx = itx * 512 + tid;
    int d = idx >> 6;
    int cl = idx & 63;
    out[ob + (size_t)d * NC + c0 + cl] = bf2f(yn[cl][d]);
  }
}

extern "C" void kernel_launch(void* const* d_in, const int* in_sizes, int n_in,
                              void* d_out, int out_size, void* d_ws, size_t ws_size,
                              hipStream_t stream)
{
  const float* residual = (const float*)d_in[0];
  const float* wq   = (const float*)d_in[1];
  const float* bq   = (const float*)d_in[2];
  const float* wk   = (const float*)d_in[3];
  const float* wv   = (const float*)d_in[5];
  const float* bv   = (const float*)d_in[6];
  const float* wo   = (const float*)d_in[7];
  const float* bo   = (const float*)d_in[8];
  const float* bn_w = (const float*)d_in[9];
  const float* bn_b = (const float*)d_in[10];
  const float* w1   = (const float*)d_in[11];
  const float* b1   = (const float*)d_in[12];
  const float* w2   = (const float*)d_in[13];
  const float* b2   = (const float*)d_in[14];
  const float* ln_w = (const float*)d_in[15];
  const float* ln_b = (const float*)d_in[16];

  char* ws = (char*)d_ws;
  short* Xb  = (short*)(ws);                        // 16 MiB  X bf16 [16384][512]
  short* YZ  = (short*)(ws + ((size_t)16 << 20));   // 16 MiB  Y -> Z -> y
  short* Hb  = (short*)(ws + ((size_t)32 << 20));   // 16 MiB  h bf16
  char*  wsw = ws + ((size_t)48 << 20);
  short* wkT = (short*)(wsw);
  short* wqT = (short*)(wsw + ((size_t)512 << 10));
  short* wvT = (short*)(wsw + ((size_t)1024 << 10));
  short* woB = (short*)(wsw + ((size_t)1536 << 10));
  short* w1B = (short*)(wsw + ((size_t)2048 << 10));
  short* w2B = (short*)(wsw + ((size_t)3072 << 10));
  short* AT  = (short*)(wsw + ((size_t)5120 << 10));
  short* MB  = (short*)(wsw + ((size_t)5632 << 10));
  float* t2  = (float*)(wsw + ((size_t)6144 << 10));
  float* c0v = (float*)(wsw + ((size_t)6144 << 10) + 2048);
  float* bnsum   = (float*)(wsw + ((size_t)6144 << 10) + 4096);
  float* bnsumsq = (float*)(wsw + ((size_t)6144 << 10) + 6144);
  float* s1col   = (float*)(wsw + ((size_t)6144 << 10) + 8192);   // 4 KiB (1024 f32)

  short* Gb = (short*)d_out;   // G bf16 16384x1024 = 32 MiB, lives in d_out until LN overwrites

  hipMemsetAsync(bnsum, 0, 4096, stream);

  // input transpose + weight prep, one launch
  pre_k<<<2888, 256, 0, stream>>>(residual, Xb, wk, wq, wv, wo, w1, w2, bq, bv, bo,
                                  wkT, wqT, wvT, woB, w1B, w2B, t2, c0v, s1col);

  // z=0: A_T[t][d]=sum_e wk[e][t]*wq[e][d]; z=1: M[e][t]=sum_d wo[e][d]*wv[d][t]
  gemm_k<4,512,512,512><<<dim3(16, 1, 2), 256, 0, stream>>>(wkT, wqT, woB, wvT,
      nullptr, nullptr, AT, MB, nullptr, nullptr, nullptr, nullptr, nullptr);

  // Y = X @ A_T^T + t2
  gemm_k<0,NROW,512,512><<<512, 256, 0, stream>>>(Xb, AT, nullptr, nullptr,
      t2, nullptr, YZ, nullptr, nullptr, nullptr, nullptr, nullptr, nullptr);
  // scores/softmax/z (in place Y->Z)
  attn_k<<<1024, 256, 0, stream>>>(Xb, YZ);
  // H = Z @ M^T + c0 + X (bf16); BN stats in fp32 pre-round
  gemm_k<1,NROW,512,512><<<512, 256, 0, stream>>>(YZ, MB, nullptr, nullptr,
      c0v, Xb, Hb, nullptr, nullptr, nullptr, nullptr, bnsum, bnsumsq);
  // G = gelu(alpha*(Hb @ W1^T) + beta*s1col + b1)   (BN folded into epilogue)
  gemm_k<2,NROW,1024,512><<<1024, 256, 0, stream>>>(Hb, w1B, nullptr, nullptr,
      b1, nullptr, Gb, nullptr, bn_w, bn_b, s1col, bnsum, bnsumsq);
  // y = G @ W2^T + b2 + alpha*Hb + beta
  gemm_k<3,NROW,512,1024><<<512, 256, 0, stream>>>(Gb, w2B, nullptr, nullptr,
      b2, Hb, YZ, nullptr, bn_w, bn_b, nullptr, bnsum, bnsumsq);
  // LayerNorm + transposed output
  ln_transpose_k<<<256, 512, 0, stream>>>(YZ, ln_w, ln_b, (float*)d_out);
}